// Round 6
// baseline (205.032 us; speedup 1.0000x reference)
//
#include <hip/hip_runtime.h>
#include <hip/hip_bf16.h>
#include <stdint.h>

// Problem constants (N,C,H,W = 4,128,64,64)
#define NB 4
#define CH 128
#define LL 4096   // H*W

typedef __attribute__((ext_vector_type(8))) short short8;   // 8 bf16 MFMA A/B frag
typedef __attribute__((ext_vector_type(4))) short short4b;  // 4 bf16 (8B)
typedef __attribute__((ext_vector_type(4))) float floatx4;  // 16x16 C/D frag
typedef __attribute__((ext_vector_type(16))) float floatx16; // 32x32 C/D frag

// Frag-major layout (verified R9-R13): element (row r, k) of 16-wide tile t:
//   t*2048 + (k>>5)*512 + ((k>>3)&3)*128 + (r&15)*8 + (k&7)
//
// R15: XCD pinning (FETCH 39.7->14.9 MB, kept).
// R18: l-split co-residency (attn_out 73->63.6, kept).
// R19 (this round):
//   - attn_out phase B: DUAL accumulators (the 16-deep 32x32x16 chain into
//     one acc was the only serial dependency chain; halve it), V chunks 0-1
//     prefetched BEFORE the barrier (compiler can't hoist loads across
//     __syncthreads), P stride 264->260 (read conflicts 4-way -> 2-way).
//   - rowsum reverted to 256x1024 R14 form: R18's 512x512 doubled Q L2
//     traffic (512 blocks x 1 MB full-Q scan vs 256).

static __device__ __forceinline__ short f2bf(float f) {
    uint32_t u = __float_as_uint(f);
    u += 0x7fffu + ((u >> 16) & 1u);
    return (short)(u >> 16);
}
static __device__ __forceinline__ float bf2f(short s) {
    return __uint_as_float(((uint32_t)(uint16_t)s) << 16);
}

// ---------------------------------------------------------------------------
// Kernel 0: W prep — Wq/Wk/Wv fp32 [o][c] -> bf16 frag-major A-layout
// (rows=o, k=c). K-scale folded into Wk. (unchanged)
// ---------------------------------------------------------------------------
__global__ __launch_bounds__(256) void wprep_kernel(
    const float* __restrict__ Wq, const float* __restrict__ Wk,
    const float* __restrict__ Wv, short* __restrict__ Wf)
{
    const int g = blockIdx.x * 256 + threadIdx.x;   // 0..49151
    const int mat = g >> 14;
    const int rem = g & 16383;
    const int o   = rem >> 7;
    const int c   = rem & 127;
    const float* W = (mat == 0) ? Wq : (mat == 1) ? Wk : Wv;
    float v = W[o * CH + c];
    if (mat == 1) v *= 0.08838834764831845f;
    Wf[(size_t)mat * 16384 + (o >> 4) * 2048 + (c >> 5) * 512
       + ((c >> 3) & 3) * 128 + (o & 15) * 8 + (c & 7)] = f2bf(v);
}

// ---------------------------------------------------------------------------
// Kernel 1: QKV projection via MFMA (R12-proven structure, unchanged).
// Outputs Qf/Kf frag-major, Vp panel [n][l>>4][c][l&15].
// grid = 512 blocks x 256 thr. XCD-pinned block remap.
// ---------------------------------------------------------------------------
__global__ __launch_bounds__(256) void proj_kernel(
    const float* __restrict__ x, const short* __restrict__ Wf,
    const float* __restrict__ bq, const float* __restrict__ bk,
    const float* __restrict__ bv,
    short* __restrict__ Qf, short* __restrict__ Kf, short* __restrict__ Vp)
{
    const int i    = blockIdx.x;
    const int n    = (i >> 1) & 3;            // XCD pair {2n,2n+1}
    const int lt   = ((i >> 3) << 1) | (i & 1); // l-tile of 32 (0..127)
    const int l0   = lt << 5;
    const int tid  = threadIdx.x;
    const int wave = tid >> 6;        // 0..3
    const int lane = tid & 63;
    const int quad = lane >> 4;
    const int mc   = lane & 15;

    __shared__ short Xb[32][136];     // [l][c] bf16, +8 pad (8.7 KB)

    {
        const int sl = tid & 31;      // l
        const int cg = tid >> 5;      // c-group of 16 (0..7)
        const float* xp = x + ((size_t)n * CH + cg * 16) * LL + l0 + sl;
        short8 buf;
        #pragma unroll
        for (int i2 = 0; i2 < 16; ++i2) {
            buf[i2 & 7] = f2bf(xp[(size_t)i2 * LL]);
            if ((i2 & 7) == 7)
                *(short8*)(void*)&Xb[sl][cg * 16 + (i2 & 8)] = buf;
        }
    }
    __syncthreads();

    const int lt2 = wave >> 1;        // l-subtile of 16
    const int oh  = wave & 1;         // o-half (4 o-tiles)
    const int gt  = lt * 2 + lt2;     // global 16-l tile index

    short8 xf[4];                     // B-frags: B[k=c][col=l]
    #pragma unroll
    for (int s = 0; s < 4; ++s)
        xf[s] = *(const short8*)(const void*)&Xb[lt2 * 16 + mc][32 * s + quad * 8];

    const size_t obase = ((size_t)n * 256 + gt) * 2048;
    const float scale = 0.08838834764831845f;  // 1/sqrt(128)

    #pragma unroll
    for (int mat = 0; mat < 3; ++mat) {
        const short* Wm = Wf + (size_t)mat * 16384;
        const float* bb = (mat == 0) ? bq : (mat == 1) ? bk : bv;
        const float bscale = (mat == 1) ? scale : 1.0f;
        #pragma unroll
        for (int ot = oh * 4; ot < oh * 4 + 4; ++ot) {
            floatx4 acc = {0.f, 0.f, 0.f, 0.f};
            #pragma unroll
            for (int s = 0; s < 4; ++s)
                acc = __builtin_amdgcn_mfma_f32_16x16x32_bf16(
                    *(const short8*)(const void*)(Wm + ot * 2048 + s * 512 + lane * 8),
                    xf[s], acc, 0, 0, 0);
            const int c0 = ot * 16 + 4 * quad;
            if (mat < 2) {
                short4b pv;
                #pragma unroll
                for (int r = 0; r < 4; ++r)
                    pv[r] = f2bf(acc[r] + bb[c0 + r] * bscale);
                short* dst = ((mat == 0) ? Qf : Kf) + obase
                           + (c0 >> 5) * 512 + ((c0 >> 3) & 3) * 128
                           + mc * 8 + (c0 & 7);
                *(short4b*)(void*)dst = pv;
            } else {
                #pragma unroll
                for (int r = 0; r < 4; ++r)
                    Vp[obase + (c0 + r) * 16 + mc] = f2bf(acc[r] + bb[c0 + r]);
            }
        }
    }
}

// ---------------------------------------------------------------------------
// Kernel 2 (reverted to R14 form): softmax denominators -> rcpD[n][l].
// 256 blocks x 1024 thr; 4 K-tiles/block (halves Q L2 traffic vs 512x512);
// ping-pong Q prefetch; XCD-pinned remap.
// ---------------------------------------------------------------------------
__global__ __launch_bounds__(1024) void rowsum_kernel(
    const short* __restrict__ Qf, const short* __restrict__ Kf,
    float* __restrict__ Dv)
{
    const int i    = blockIdx.x;         // 256 blocks
    const int n    = (i >> 1) & 3;       // XCD pair {2n,2n+1}
    const int tq   = ((i >> 3) << 1) | (i & 1);  // 64-l group (0..63)
    const int tid  = threadIdx.x;
    const int wave = tid >> 6;           // 0..15
    const int lane = tid & 63;
    const int quad = lane >> 4;
    const int mc   = lane & 15;
    const int mw   = wave & 7;           // m-eighth (512 m = 32 q-tiles)
    const int th   = wave >> 3;          // K-tile half (2 of the 4 tiles)

    __shared__ float Db[16][32];         // per-wave partial D (2 KB)

    const short* Kb = Kf + ((size_t)n * 256 + tq * 4 + th * 2) * 2048 + lane * 8;
    short8 kf[2][4];
    #pragma unroll
    for (int t = 0; t < 2; ++t)
        #pragma unroll
        for (int s = 0; s < 4; ++s)
            kf[t][s] = *(const short8*)(const void*)(Kb + t * 2048 + s * 512);

    const short* Qn = Qf + (size_t)n * 524288 + (size_t)mw * 32 * 2048 + lane * 8;
    float rs[2][4] = {{0.f, 0.f, 0.f, 0.f}, {0.f, 0.f, 0.f, 0.f}};

    short8 qA[4], qB[4];
    #pragma unroll
    for (int s = 0; s < 4; ++s)
        qA[s] = *(const short8*)(const void*)(Qn + s * 512);

    auto qstep = [&](const short8 (&q)[4]) {
        floatx4 a0 = {0.f, 0.f, 0.f, 0.f};
        floatx4 a1 = {0.f, 0.f, 0.f, 0.f};
        #pragma unroll
        for (int s = 0; s < 4; ++s) {
            a0 = __builtin_amdgcn_mfma_f32_16x16x32_bf16(kf[0][s], q[s], a0, 0, 0, 0);
            a1 = __builtin_amdgcn_mfma_f32_16x16x32_bf16(kf[1][s], q[s], a1, 0, 0, 0);
        }
        #pragma unroll
        for (int r = 0; r < 4; ++r) {
            rs[0][r] += __expf(a0[r]);
            rs[1][r] += __expf(a1[r]);
        }
    };

    for (int it = 0; it < 32; it += 2) {
        #pragma unroll
        for (int s = 0; s < 4; ++s)
            qB[s] = *(const short8*)(const void*)(
                Qn + (size_t)((it + 1) & 31) * 2048 + s * 512);
        qstep(qA);
        #pragma unroll
        for (int s = 0; s < 4; ++s)
            qA[s] = *(const short8*)(const void*)(
                Qn + (size_t)((it + 2) & 31) * 2048 + s * 512);
        qstep(qB);
    }

    #pragma unroll
    for (int t = 0; t < 2; ++t)
        #pragma unroll
        for (int r = 0; r < 4; ++r) {
            float v = rs[t][r];
            v += __shfl_xor(v, 1);
            v += __shfl_xor(v, 2);
            v += __shfl_xor(v, 4);
            v += __shfl_xor(v, 8);
            if (mc == 0) Db[wave][t * 16 + quad * 4 + r] = v;
        }
    __syncthreads();
    if (tid < 64) {
        const int lh = tid >> 5, lr = tid & 31;
        float s = 0.f;
        #pragma unroll
        for (int m = 0; m < 8; ++m) s += Db[lh * 8 + m][lr];
        Dv[(size_t)n * 4096 + tq * 64 + tid] = 1.0f / s;
    }
}

// ---------------------------------------------------------------------------
// Kernel 3 (R19): partial O over an l-half.
// grid 512 = {n, m-block 64, l-half} x 512 thr (8 waves), 2 blocks/CU.
// 8 steps of 256 l; phase A: wave w -> l-tiles 2w,2w+1; phase B: wave
// (ct,mh) -> full 256-l sum with DUAL accumulators (even/odd chunks);
// V chunks 0-1 prefetched before the barrier; P stride 260 (2-way reads).
// Writes partial O f32 to Po[lh][n][c][m].
// ---------------------------------------------------------------------------
__global__ __launch_bounds__(512, 4) void attn_out_kernel(
    const short* __restrict__ Qf, const short* __restrict__ Kf,
    const short* __restrict__ Vp, const float* __restrict__ Dv,
    float* __restrict__ Po)
{
    const int i    = blockIdx.x;
    const int n    = (i >> 1) & 3;               // XCD pair {2n,2n+1}
    const int j    = ((i >> 3) << 1) | (i & 1);  // 0..127
    const int lh   = j >> 6;                     // l-half
    const int mb   = j & 63;                     // m-block (0..63)
    const int m0   = mb << 6;
    const int tid  = threadIdx.x;
    const int wave = tid >> 6;          // 0..7
    const int lane = tid & 63;
    const int quad = lane >> 4;
    const int mc   = lane & 15;
    const int l32  = lane & 31;
    const int h    = lane >> 5;
    const int ct   = wave & 3;          // phase B c-tile (32 channels)
    const int mh   = wave >> 2;         // phase B m-half (32 cols)

    __shared__ short P[2][64][260];     // dbuf [m][l-local 256 +4] (65 KB)

    const short* Qn  = Qf + (size_t)n * 524288;
    const short* Kn  = Kf + (size_t)n * 524288;
    const short* Vpn = Vp + (size_t)n * 524288;
    const float* Dn  = Dv + (size_t)n * 4096;
    const int tile0  = lh * 128;        // first 16-l tile of this half

    const size_t vcol = (size_t)(32 * ct + l32) * 16 + 8 * h;

    floatx16 acc0, acc1;
    #pragma unroll
    for (int r = 0; r < 16; ++r) { acc0[r] = 0.f; acc1[r] = 0.f; }

    for (int t = 0; t < 8; ++t) {
        const int p   = t & 1;
        const int tb0 = tile0 + t * 16;

        // ---- phase A: wave w -> l-tiles {2w, 2w+1} of step t, 64 m ----
        {
            const int tb = tb0 + 2 * wave;
            short8 kfr[2][4];
            #pragma unroll
            for (int jj = 0; jj < 2; ++jj)
                #pragma unroll
                for (int s = 0; s < 4; ++s)
                    kfr[jj][s] = *(const short8*)(const void*)(
                        Kn + (size_t)(tb + jj) * 2048 + s * 512 + lane * 8);
            floatx4 dr[2];
            #pragma unroll
            for (int jj = 0; jj < 2; ++jj)
                dr[jj] = *(const floatx4*)(const void*)(
                    Dn + (tb + jj) * 16 + quad * 4);

            #pragma unroll
            for (int mst = 0; mst < 4; ++mst) {
                short8 qt[4];
                #pragma unroll
                for (int s = 0; s < 4; ++s)
                    qt[s] = *(const short8*)(const void*)(
                        Qn + (size_t)((m0 >> 4) + mst) * 2048 + s * 512 + lane * 8);
                floatx4 sa0 = {0.f, 0.f, 0.f, 0.f};
                floatx4 sa1 = {0.f, 0.f, 0.f, 0.f};
                #pragma unroll
                for (int s = 0; s < 4; ++s) {
                    sa0 = __builtin_amdgcn_mfma_f32_16x16x32_bf16(kfr[0][s], qt[s], sa0, 0, 0, 0);
                    sa1 = __builtin_amdgcn_mfma_f32_16x16x32_bf16(kfr[1][s], qt[s], sa1, 0, 0, 0);
                }
                short4b pv0, pv1;
                #pragma unroll
                for (int r = 0; r < 4; ++r) {
                    pv0[r] = f2bf(__expf(sa0[r]) * dr[0][r]);
                    pv1[r] = f2bf(__expf(sa1[r]) * dr[1][r]);
                }
                // C-layout (row=l=4q+r, col=m=mc) -> P[m][l-local]
                *(short4b*)(void*)&P[p][16 * mst + mc][32 * wave + quad * 4] = pv0;
                *(short4b*)(void*)&P[p][16 * mst + mc][32 * wave + 16 + quad * 4] = pv1;
            }
        }

        // ---- prefetch V chunks 0,1 (global, independent of P) ----
        const short8 vp0 = *(const short8*)(const void*)(
            Vpn + (size_t)(tb0 + 0) * 2048 + vcol);
        const short8 vp1 = *(const short8*)(const void*)(
            Vpn + (size_t)(tb0 + 1) * 2048 + vcol);

        __syncthreads();   // only barrier: P[p] visible

        // ---- phase B: dual-chain 256-l sum, 16 chunks ----
        {
            const short8 pf0 = *(const short8*)(const void*)&P[p][32 * mh + l32][8 * h];
            acc0 = __builtin_amdgcn_mfma_f32_32x32x16_bf16(vp0, pf0, acc0, 0, 0, 0);
            const short8 pf1 = *(const short8*)(const void*)&P[p][32 * mh + l32][16 + 8 * h];
            acc1 = __builtin_amdgcn_mfma_f32_32x32x16_bf16(vp1, pf1, acc1, 0, 0, 0);
        }
        #pragma unroll
        for (int kc = 2; kc < 16; kc += 2) {
            const short8 vfa = *(const short8*)(const void*)(
                Vpn + (size_t)(tb0 + kc) * 2048 + vcol);
            const short8 pfa = *(const short8*)(const void*)&P[p][32 * mh + l32][16 * kc + 8 * h];
            acc0 = __builtin_amdgcn_mfma_f32_32x32x16_bf16(vfa, pfa, acc0, 0, 0, 0);
            const short8 vfb = *(const short8*)(const void*)(
                Vpn + (size_t)(tb0 + kc + 1) * 2048 + vcol);
            const short8 pfb = *(const short8*)(const void*)&P[p][32 * mh + l32][16 * (kc + 1) + 8 * h];
            acc1 = __builtin_amdgcn_mfma_f32_32x32x16_bf16(vfb, pfb, acc1, 0, 0, 0);
        }
        // no trailing barrier: next step writes P[p^1] (safe: one barrier
        // separates any read of P[p] from the next write of P[p])
    }

    // ---- epilogue: write partial O (f32), 32x32 C-layout ----
    float* Pon = Po + (size_t)(lh * 4 + n) * 524288;  // [lh][n][c][m]
    #pragma unroll
    for (int r = 0; r < 16; ++r) {
        const int c = 32 * ct + (r & 3) + 8 * (r >> 2) + 4 * h;
        const int m = m0 + 32 * mh + l32;
        Pon[(size_t)c * LL + m] = acc0[r] + acc1[r];
    }
}

// ---------------------------------------------------------------------------
// Kernel 4: out = x + Po[0] + Po[1].  524288 float4s, 1 per thread.
// ---------------------------------------------------------------------------
__global__ __launch_bounds__(256) void combine_kernel(
    const float* __restrict__ x, const float* __restrict__ Po,
    float* __restrict__ out)
{
    const size_t k = (size_t)blockIdx.x * 256 + threadIdx.x;  // float4 idx
    const floatx4 a = *(const floatx4*)(const void*)(x + 4 * k);
    const floatx4 b = *(const floatx4*)(const void*)(Po + 4 * k);
    const floatx4 c = *(const floatx4*)(const void*)(Po + 2097152 + 4 * k);
    floatx4 o;
    #pragma unroll
    for (int r = 0; r < 4; ++r) o[r] = a[r] + b[r] + c[r];
    *(floatx4*)(void*)(out + 4 * k) = o;
}

// ---------------------------------------------------------------------------
extern "C" void kernel_launch(void* const* d_in, const int* in_sizes, int n_in,
                              void* d_out, int out_size, void* d_ws, size_t ws_size,
                              hipStream_t stream) {
    (void)in_sizes; (void)n_in; (void)out_size; (void)ws_size;
    const float* x  = (const float*)d_in[0];
    const float* Wq = (const float*)d_in[1];
    const float* bq = (const float*)d_in[2];
    const float* Wk = (const float*)d_in[3];
    const float* bk = (const float*)d_in[4];
    const float* Wv = (const float*)d_in[5];
    const float* bv = (const float*)d_in[6];
    float* out = (float*)d_out;

    char* ws = (char*)d_ws;
    // ws: Qf 4MB | Kf 4MB | Vp 4MB | Dv 64KB | Wf 96KB+pad | Po 16MB (~33MB)
    short* Qf = (short*)(ws);
    short* Kf = (short*)(ws + 4194304);
    short* Vp = (short*)(ws + 8388608);
    float* Dv = (float*)(ws + 12582912);
    short* Wf = (short*)(ws + 16777216);
    float* Po = (float*)(ws + 16908288);

    wprep_kernel<<<192, 256, 0, stream>>>(Wq, Wk, Wv, Wf);
    proj_kernel<<<512, 256, 0, stream>>>(x, Wf, bq, bk, bv, Qf, Kf, Vp);
    rowsum_kernel<<<256, 1024, 0, stream>>>(Qf, Kf, Dv);
    attn_out_kernel<<<512, 512, 0, stream>>>(Qf, Kf, Vp, Dv, Po);
    combine_kernel<<<2048, 256, 0, stream>>>(x, Po, out);
}

// Round 7
// 174.222 us; speedup vs baseline: 1.1768x; 1.1768x over previous
//
#include <hip/hip_runtime.h>
#include <hip/hip_bf16.h>
#include <stdint.h>

// Problem constants (N,C,H,W = 4,128,64,64)
#define NB 4
#define CH 128
#define LL 4096   // H*W

typedef __attribute__((ext_vector_type(8))) short short8;   // 8 bf16 MFMA A/B frag
typedef __attribute__((ext_vector_type(4))) short short4b;  // 4 bf16 (8B)
typedef __attribute__((ext_vector_type(4))) float floatx4;  // 16x16 C/D frag
typedef __attribute__((ext_vector_type(16))) float floatx16; // 32x32 C/D frag

// Frag-major layout (verified R9-R13): element (row r, k) of 16-wide tile t:
//   t*2048 + (k>>5)*512 + ((k>>3)&3)*128 + (r&15)*8 + (k&7)
//
// R15: XCD pinning (FETCH 39.7->14.9 MB, kept).
// R18: l-split co-residency (kept).
// R19 lessons: dual-acc/V-prefetch (+24 regs) -> spill cliff (FETCH 137MB).
//   Stride 260 zeroed LDS conflicts (kept, free).
// R20 (this round): RESIDENT Q at 8-wave scale. R5 reloaded Q per mst per
//   step (16 serialized L2 loads/wave/interval, ~500cy each exposed — the
//   dominant stall per the cycle model; true MFMA occupancy ~6%). Phase A
//   remapped: wave owns 2 m-tiles x 4 l-tiles -> qf[2][4] = 32 regs
//   resident, kfr 16 transient. Peak live ~95 < 128 (no spill expected).
//   Phase B / grid / rowsum / proj identical to R5.

static __device__ __forceinline__ short f2bf(float f) {
    uint32_t u = __float_as_uint(f);
    u += 0x7fffu + ((u >> 16) & 1u);
    return (short)(u >> 16);
}
static __device__ __forceinline__ float bf2f(short s) {
    return __uint_as_float(((uint32_t)(uint16_t)s) << 16);
}

// ---------------------------------------------------------------------------
// Kernel 0: W prep — Wq/Wk/Wv fp32 [o][c] -> bf16 frag-major A-layout
// (rows=o, k=c). K-scale folded into Wk. (unchanged)
// ---------------------------------------------------------------------------
__global__ __launch_bounds__(256) void wprep_kernel(
    const float* __restrict__ Wq, const float* __restrict__ Wk,
    const float* __restrict__ Wv, short* __restrict__ Wf)
{
    const int g = blockIdx.x * 256 + threadIdx.x;   // 0..49151
    const int mat = g >> 14;
    const int rem = g & 16383;
    const int o   = rem >> 7;
    const int c   = rem & 127;
    const float* W = (mat == 0) ? Wq : (mat == 1) ? Wk : Wv;
    float v = W[o * CH + c];
    if (mat == 1) v *= 0.08838834764831845f;
    Wf[(size_t)mat * 16384 + (o >> 4) * 2048 + (c >> 5) * 512
       + ((c >> 3) & 3) * 128 + (o & 15) * 8 + (c & 7)] = f2bf(v);
}

// ---------------------------------------------------------------------------
// Kernel 1: QKV projection via MFMA (R12-proven structure, unchanged).
// Outputs Qf/Kf frag-major, Vp panel [n][l>>4][c][l&15].
// grid = 512 blocks x 256 thr. XCD-pinned block remap.
// ---------------------------------------------------------------------------
__global__ __launch_bounds__(256) void proj_kernel(
    const float* __restrict__ x, const short* __restrict__ Wf,
    const float* __restrict__ bq, const float* __restrict__ bk,
    const float* __restrict__ bv,
    short* __restrict__ Qf, short* __restrict__ Kf, short* __restrict__ Vp)
{
    const int i    = blockIdx.x;
    const int n    = (i >> 1) & 3;            // XCD pair {2n,2n+1}
    const int lt   = ((i >> 3) << 1) | (i & 1); // l-tile of 32 (0..127)
    const int l0   = lt << 5;
    const int tid  = threadIdx.x;
    const int wave = tid >> 6;        // 0..3
    const int lane = tid & 63;
    const int quad = lane >> 4;
    const int mc   = lane & 15;

    __shared__ short Xb[32][136];     // [l][c] bf16, +8 pad (8.7 KB)

    {
        const int sl = tid & 31;      // l
        const int cg = tid >> 5;      // c-group of 16 (0..7)
        const float* xp = x + ((size_t)n * CH + cg * 16) * LL + l0 + sl;
        short8 buf;
        #pragma unroll
        for (int i2 = 0; i2 < 16; ++i2) {
            buf[i2 & 7] = f2bf(xp[(size_t)i2 * LL]);
            if ((i2 & 7) == 7)
                *(short8*)(void*)&Xb[sl][cg * 16 + (i2 & 8)] = buf;
        }
    }
    __syncthreads();

    const int lt2 = wave >> 1;        // l-subtile of 16
    const int oh  = wave & 1;         // o-half (4 o-tiles)
    const int gt  = lt * 2 + lt2;     // global 16-l tile index

    short8 xf[4];                     // B-frags: B[k=c][col=l]
    #pragma unroll
    for (int s = 0; s < 4; ++s)
        xf[s] = *(const short8*)(const void*)&Xb[lt2 * 16 + mc][32 * s + quad * 8];

    const size_t obase = ((size_t)n * 256 + gt) * 2048;
    const float scale = 0.08838834764831845f;  // 1/sqrt(128)

    #pragma unroll
    for (int mat = 0; mat < 3; ++mat) {
        const short* Wm = Wf + (size_t)mat * 16384;
        const float* bb = (mat == 0) ? bq : (mat == 1) ? bk : bv;
        const float bscale = (mat == 1) ? scale : 1.0f;
        #pragma unroll
        for (int ot = oh * 4; ot < oh * 4 + 4; ++ot) {
            floatx4 acc = {0.f, 0.f, 0.f, 0.f};
            #pragma unroll
            for (int s = 0; s < 4; ++s)
                acc = __builtin_amdgcn_mfma_f32_16x16x32_bf16(
                    *(const short8*)(const void*)(Wm + ot * 2048 + s * 512 + lane * 8),
                    xf[s], acc, 0, 0, 0);
            const int c0 = ot * 16 + 4 * quad;
            if (mat < 2) {
                short4b pv;
                #pragma unroll
                for (int r = 0; r < 4; ++r)
                    pv[r] = f2bf(acc[r] + bb[c0 + r] * bscale);
                short* dst = ((mat == 0) ? Qf : Kf) + obase
                           + (c0 >> 5) * 512 + ((c0 >> 3) & 3) * 128
                           + mc * 8 + (c0 & 7);
                *(short4b*)(void*)dst = pv;
            } else {
                #pragma unroll
                for (int r = 0; r < 4; ++r)
                    Vp[obase + (c0 + r) * 16 + mc] = f2bf(acc[r] + bb[c0 + r]);
            }
        }
    }
}

// ---------------------------------------------------------------------------
// Kernel 2: softmax denominators -> rcpD[n][l]. (R18/R5 form, unchanged)
// 512 blocks x 512 thr (2 blocks/CU), block = 32 l (2 K-tiles); wave w
// owns m-eighth, ping-pong Q prefetch.
// ---------------------------------------------------------------------------
__global__ __launch_bounds__(512, 4) void rowsum_kernel(
    const short* __restrict__ Qf, const short* __restrict__ Kf,
    float* __restrict__ Dv)
{
    const int i    = blockIdx.x;         // 512 blocks
    const int n    = (i >> 1) & 3;       // XCD pair {2n,2n+1}
    const int tp   = ((i >> 3) << 1) | (i & 1);  // 32-l group (0..127)
    const int tid  = threadIdx.x;
    const int wave = tid >> 6;           // 0..7 = m-eighth
    const int lane = tid & 63;
    const int quad = lane >> 4;
    const int mc   = lane & 15;

    __shared__ float Db[8][32];          // per-wave partial D (1 KB)

    const short* Kb = Kf + ((size_t)n * 256 + tp * 2) * 2048 + lane * 8;
    short8 kf[2][4];
    #pragma unroll
    for (int t = 0; t < 2; ++t)
        #pragma unroll
        for (int s = 0; s < 4; ++s)
            kf[t][s] = *(const short8*)(const void*)(Kb + t * 2048 + s * 512);

    const short* Qn = Qf + (size_t)n * 524288 + (size_t)wave * 32 * 2048 + lane * 8;
    float rs[2][4] = {{0.f, 0.f, 0.f, 0.f}, {0.f, 0.f, 0.f, 0.f}};

    short8 qA[4], qB[4];
    #pragma unroll
    for (int s = 0; s < 4; ++s)
        qA[s] = *(const short8*)(const void*)(Qn + s * 512);

    auto qstep = [&](const short8 (&q)[4]) {
        floatx4 a0 = {0.f, 0.f, 0.f, 0.f};
        floatx4 a1 = {0.f, 0.f, 0.f, 0.f};
        #pragma unroll
        for (int s = 0; s < 4; ++s) {
            a0 = __builtin_amdgcn_mfma_f32_16x16x32_bf16(kf[0][s], q[s], a0, 0, 0, 0);
            a1 = __builtin_amdgcn_mfma_f32_16x16x32_bf16(kf[1][s], q[s], a1, 0, 0, 0);
        }
        #pragma unroll
        for (int r = 0; r < 4; ++r) {
            rs[0][r] += __expf(a0[r]);
            rs[1][r] += __expf(a1[r]);
        }
    };

    for (int it = 0; it < 32; it += 2) {
        #pragma unroll
        for (int s = 0; s < 4; ++s)
            qB[s] = *(const short8*)(const void*)(
                Qn + (size_t)((it + 1) & 31) * 2048 + s * 512);
        qstep(qA);
        #pragma unroll
        for (int s = 0; s < 4; ++s)
            qA[s] = *(const short8*)(const void*)(
                Qn + (size_t)((it + 2) & 31) * 2048 + s * 512);
        qstep(qB);
    }

    #pragma unroll
    for (int t = 0; t < 2; ++t)
        #pragma unroll
        for (int r = 0; r < 4; ++r) {
            float v = rs[t][r];
            v += __shfl_xor(v, 1);
            v += __shfl_xor(v, 2);
            v += __shfl_xor(v, 4);
            v += __shfl_xor(v, 8);
            if (mc == 0) Db[wave][t * 16 + quad * 4 + r] = v;
        }
    __syncthreads();
    if (tid < 32) {
        float s = 0.f;
        #pragma unroll
        for (int m = 0; m < 8; ++m) s += Db[m][tid];
        Dv[(size_t)n * 4096 + tp * 32 + tid] = 1.0f / s;
    }
}

// ---------------------------------------------------------------------------
// Kernel 3 (R20): partial O over an l-half.
// grid 512 = {n, m-block 64, l-half} x 512 thr (8 waves), 2 blocks/CU.
// 8 steps of 256 l. Phase A: wave (mq=w&1, lq=w>>1) -> 2 m-tiles x 4
// l-tiles with RESIDENT qf[2][4] (32 regs, loaded once). Phase B: wave
// (ct=w&3, mh=w>>2) -> full 256-l sum, single acc (R5-proven). P stride
// 260 (conflict-free, R6-proven). Writes partial O f32 to Po[lh][n][c][m].
// ---------------------------------------------------------------------------
__global__ __launch_bounds__(512, 4) void attn_out_kernel(
    const short* __restrict__ Qf, const short* __restrict__ Kf,
    const short* __restrict__ Vp, const float* __restrict__ Dv,
    float* __restrict__ Po)
{
    const int i    = blockIdx.x;
    const int n    = (i >> 1) & 3;               // XCD pair {2n,2n+1}
    const int j    = ((i >> 3) << 1) | (i & 1);  // 0..127
    const int lh   = j >> 6;                     // l-half
    const int mb   = j & 63;                     // m-block (0..63)
    const int m0   = mb << 6;
    const int tid  = threadIdx.x;
    const int wave = tid >> 6;          // 0..7
    const int lane = tid & 63;
    const int quad = lane >> 4;
    const int mc   = lane & 15;
    const int l32  = lane & 31;
    const int h    = lane >> 5;
    const int mq   = wave & 1;          // phase A m-half (2 m-tiles)
    const int lq   = wave >> 1;         // phase A l-quarter (4 l-tiles)
    const int ct   = wave & 3;          // phase B c-tile (32 channels)
    const int mh   = wave >> 2;         // phase B m-half (32 cols)

    __shared__ short P[2][64][260];     // dbuf [m][l-local 256 +4] (65 KB)

    const short* Qn  = Qf + (size_t)n * 524288;
    const short* Kn  = Kf + (size_t)n * 524288;
    const short* Vpn = Vp + (size_t)n * 524288;
    const float* Dn  = Dv + (size_t)n * 4096;
    const int tile0  = lh * 128;        // first 16-l tile of this half

    const size_t vcol = (size_t)(32 * ct + l32) * 16 + 8 * h;

    // resident Q B-frags for this wave's 2 m-tiles (32 VGPR, loaded once)
    short8 qf[2][4];
    #pragma unroll
    for (int ms = 0; ms < 2; ++ms)
        #pragma unroll
        for (int s = 0; s < 4; ++s)
            qf[ms][s] = *(const short8*)(const void*)(
                Qn + (size_t)(mb * 4 + mq * 2 + ms) * 2048 + s * 512 + lane * 8);

    floatx16 acc;
    #pragma unroll
    for (int r = 0; r < 16; ++r) acc[r] = 0.f;

    for (int t = 0; t < 8; ++t) {
        const int p   = t & 1;
        const int tb0 = tile0 + t * 16;

        // ---- phase A: wave (mq,lq) -> m-tiles {2mq,2mq+1} x l-tiles
        //      {4lq..4lq+3} of step t; K transient 16 regs/tile ----
        #pragma unroll
        for (int tl = 0; tl < 4; ++tl) {
            const int tb = tb0 + lq * 4 + tl;
            short8 kfr[4];
            #pragma unroll
            for (int s = 0; s < 4; ++s)
                kfr[s] = *(const short8*)(const void*)(
                    Kn + (size_t)tb * 2048 + s * 512 + lane * 8);
            const floatx4 drt = *(const floatx4*)(const void*)(
                Dn + tb * 16 + quad * 4);

            #pragma unroll
            for (int ms = 0; ms < 2; ++ms) {
                floatx4 sa = {0.f, 0.f, 0.f, 0.f};
                #pragma unroll
                for (int s = 0; s < 4; ++s)
                    sa = __builtin_amdgcn_mfma_f32_16x16x32_bf16(kfr[s], qf[ms][s], sa, 0, 0, 0);
                short4b pv;
                #pragma unroll
                for (int r = 0; r < 4; ++r)
                    pv[r] = f2bf(__expf(sa[r]) * drt[r]);
                // C-layout (row=l=4q+r, col=m=mc) -> P[m][l-local]
                *(short4b*)(void*)&P[p][16 * (mq * 2 + ms) + mc]
                                    [(lq * 4 + tl) * 16 + quad * 4] = pv;
            }
        }
        __syncthreads();   // only barrier: P[p] visible

        // ---- phase B: wave (ct,mh): full 256-l sum, 16 chunks (R5) ----
        #pragma unroll
        for (int kc = 0; kc < 16; ++kc) {
            const short8 vf = *(const short8*)(const void*)(
                Vpn + (size_t)(tb0 + kc) * 2048 + vcol);
            const short8 pf = *(const short8*)(const void*)&P[p][32 * mh + l32][16 * kc + 8 * h];
            acc = __builtin_amdgcn_mfma_f32_32x32x16_bf16(vf, pf, acc, 0, 0, 0);
        }
        // no trailing barrier: next step writes P[p^1] (one barrier
        // separates any read of P[p] from the next write of P[p])
    }

    // ---- epilogue: write partial O (f32), 32x32 C-layout ----
    float* Pon = Po + (size_t)(lh * 4 + n) * 524288;  // [lh][n][c][m]
    #pragma unroll
    for (int r = 0; r < 16; ++r) {
        const int c = 32 * ct + (r & 3) + 8 * (r >> 2) + 4 * h;
        const int m = m0 + 32 * mh + l32;
        Pon[(size_t)c * LL + m] = acc[r];
    }
}

// ---------------------------------------------------------------------------
// Kernel 4: out = x + Po[0] + Po[1].  524288 float4s, 1 per thread.
// ---------------------------------------------------------------------------
__global__ __launch_bounds__(256) void combine_kernel(
    const float* __restrict__ x, const float* __restrict__ Po,
    float* __restrict__ out)
{
    const size_t k = (size_t)blockIdx.x * 256 + threadIdx.x;  // float4 idx
    const floatx4 a = *(const floatx4*)(const void*)(x + 4 * k);
    const floatx4 b = *(const floatx4*)(const void*)(Po + 4 * k);
    const floatx4 c = *(const floatx4*)(const void*)(Po + 2097152 + 4 * k);
    floatx4 o;
    #pragma unroll
    for (int r = 0; r < 4; ++r) o[r] = a[r] + b[r] + c[r];
    *(floatx4*)(void*)(out + 4 * k) = o;
}

// ---------------------------------------------------------------------------
extern "C" void kernel_launch(void* const* d_in, const int* in_sizes, int n_in,
                              void* d_out, int out_size, void* d_ws, size_t ws_size,
                              hipStream_t stream) {
    (void)in_sizes; (void)n_in; (void)out_size; (void)ws_size;
    const float* x  = (const float*)d_in[0];
    const float* Wq = (const float*)d_in[1];
    const float* bq = (const float*)d_in[2];
    const float* Wk = (const float*)d_in[3];
    const float* bk = (const float*)d_in[4];
    const float* Wv = (const float*)d_in[5];
    const float* bv = (const float*)d_in[6];
    float* out = (float*)d_out;

    char* ws = (char*)d_ws;
    // ws: Qf 4MB | Kf 4MB | Vp 4MB | Dv 64KB | Wf 96KB+pad | Po 16MB (~33MB)
    short* Qf = (short*)(ws);
    short* Kf = (short*)(ws + 4194304);
    short* Vp = (short*)(ws + 8388608);
    float* Dv = (float*)(ws + 12582912);
    short* Wf = (short*)(ws + 16777216);
    float* Po = (float*)(ws + 16908288);

    wprep_kernel<<<192, 256, 0, stream>>>(Wq, Wk, Wv, Wf);
    proj_kernel<<<512, 256, 0, stream>>>(x, Wf, bq, bk, bv, Qf, Kf, Vp);
    rowsum_kernel<<<512, 512, 0, stream>>>(Qf, Kf, Dv);
    attn_out_kernel<<<512, 512, 0, stream>>>(Qf, Kf, Vp, Dv, Po);
    combine_kernel<<<2048, 256, 0, stream>>>(x, Po, out);
}